// Round 1
// baseline (7452.986 us; speedup 1.0000x reference)
//
#include <hip/hip_runtime.h>
#include <hip/hip_bf16.h>

#define NB 32      // batch
#define NS 256     // seq len
#define NI 1024    // input size
#define NO 1024    // hidden size
#define NK 2048    // NI + NO
#define NC 4096    // 4 * NO
#define LN_EPS 1e-5f

typedef __attribute__((ext_vector_type(4))) float f32x4;
typedef __attribute__((ext_vector_type(4))) unsigned int u32x4;

// MFMA via inline asm: avoids builtin signature ambiguity (short8 vs v8bf16).
// D/C tied via "+v". Hazard nops handled by callers.
__device__ __forceinline__ f32x4 mfma_bf16_16x16x32(u32x4 a, u32x4 b, f32x4 c) {
  asm volatile("v_mfma_f32_16x16x32_bf16 %0, %1, %2, %0" : "+v"(c) : "v"(a), "v"(b));
  return c;
}

__device__ __forceinline__ float sigf(float x) { return 1.0f / (1.0f + __expf(-x)); }

// ---------------- setup kernels ----------------

// x (fp32, B*S*NI) -> bf16
__global__ void convert_x(const float* __restrict__ x, __hip_bfloat16* __restrict__ xbf) {
  size_t i = ((size_t)blockIdx.x * 256 + threadIdx.x) * 4;
  float4 v = *(const float4*)(x + i);
  xbf[i + 0] = __float2bfloat16(v.x);
  xbf[i + 1] = __float2bfloat16(v.y);
  xbf[i + 2] = __float2bfloat16(v.z);
  xbf[i + 3] = __float2bfloat16(v.w);
}

// W (fp32, [k=2048][n=4096]) -> WT bf16 [n][k]   (64x64 LDS tile transpose)
__global__ void transpose_w(const float* __restrict__ W, __hip_bfloat16* __restrict__ WT) {
  __shared__ float tile[64][65];
  const int b  = blockIdx.x;         // 32 k-tiles * 64 n-tiles
  const int k0 = (b & 31) * 64;
  const int n0 = (b >> 5) * 64;
  const int tid = threadIdx.x;       // 256
  const int r = tid >> 6;            // 0..3
  const int c = tid & 63;            // 0..63
#pragma unroll
  for (int i = 0; i < 16; ++i) {
    const int rr = i * 4 + r;
    tile[rr][c] = W[(size_t)(k0 + rr) * NC + n0 + c];
  }
  __syncthreads();
#pragma unroll
  for (int i = 0; i < 16; ++i) {
    const int rr = i * 4 + r;
    WT[(size_t)(n0 + rr) * NK + k0 + c] = __float2bfloat16(tile[c][rr]);
  }
}

// init h (bf16 + fp32) and c from init_hx/init_cx (broadcast row 0)
__global__ void init_state(const float* __restrict__ hx0, const float* __restrict__ cx0,
                           __hip_bfloat16* __restrict__ hbf, float* __restrict__ cst,
                           float* __restrict__ hf) {
  const int i = blockIdx.x * 256 + threadIdx.x;  // 32768 = NB*NO
  const int j = i & (NO - 1);
  const float hv = hx0[j];
  hbf[i] = __float2bfloat16(hv);
  hf[i]  = hv;
  cst[i] = cx0[j];
}

// ---------------- per-step kernels (main, bf16 MFMA) ----------------

// grid 256 x 64 threads (1 wave/block). Block w: mt = w&1 (batch-row tile),
// n0 = (w>>1)*32 (two 16-wide n tiles). comb = [x_t, h] @ W + b, plus
// per-row (sum, sumsq) partials for the LN.
__launch_bounds__(64)
__global__ void step_gemm(const __hip_bfloat16* __restrict__ xbf,
                          const __hip_bfloat16* __restrict__ hbf,
                          const __hip_bfloat16* __restrict__ WT,
                          const float* __restrict__ bias,
                          float* __restrict__ comb,
                          float* __restrict__ partials,
                          int t) {
  const int w    = blockIdx.x;
  const int mt   = w & 1;
  const int n0   = (w >> 1) * 32;
  const int lane = threadIdx.x;
  const int q    = lane >> 4;
  const int ln   = lane & 15;
  const int m    = mt * 16 + ln;   // A row for this lane

  const __hip_bfloat16* ax  = xbf + ((size_t)m * NS + t) * NI + q * 8;
  const __hip_bfloat16* ah  = hbf + (size_t)m * NO + q * 8;
  const __hip_bfloat16* bp0 = WT + (size_t)(n0 + ln) * NK + q * 8;
  const __hip_bfloat16* bp1 = WT + (size_t)(n0 + 16 + ln) * NK + q * 8;

  f32x4 acc0 = {0.f, 0.f, 0.f, 0.f};
  f32x4 acc1 = {0.f, 0.f, 0.f, 0.f};

  asm volatile("s_nop 1" ::);  // VALU-write(acc init) -> MFMA-read-C hazard
#pragma unroll 4
  for (int kt = 0; kt < 32; ++kt) {  // x part of K
    u32x4 a  = *(const u32x4*)(ax + kt * 32);
    u32x4 b0 = *(const u32x4*)(bp0 + kt * 32);
    u32x4 b1 = *(const u32x4*)(bp1 + kt * 32);
    acc0 = mfma_bf16_16x16x32(a, b0, acc0);
    acc1 = mfma_bf16_16x16x32(a, b1, acc1);
  }
#pragma unroll 4
  for (int kt = 0; kt < 32; ++kt) {  // h part of K
    u32x4 a  = *(const u32x4*)(ah + kt * 32);
    u32x4 b0 = *(const u32x4*)(bp0 + NI + kt * 32);
    u32x4 b1 = *(const u32x4*)(bp1 + NI + kt * 32);
    acc0 = mfma_bf16_16x16x32(a, b0, acc0);
    acc1 = mfma_bf16_16x16x32(a, b1, acc1);
  }
  asm volatile("s_nop 7\n\ts_nop 7" ::);  // MFMA-write -> VALU-read hazard

  // D layout: col = lane&15 (+tile n), row = quad*4 + reg
#pragma unroll
  for (int r = 0; r < 4; ++r) {
    const int mm = mt * 16 + q * 4 + r;
    const int nA = n0 + ln;
    const int nB = n0 + 16 + ln;
    const float v0 = acc0[r] + bias[nA];
    const float v1 = acc1[r] + bias[nB];
    comb[(size_t)mm * NC + nA] = v0;
    comb[(size_t)mm * NC + nB] = v1;
    float s  = v0 + v1;
    float ss = v0 * v0 + v1 * v1;
#pragma unroll
    for (int off = 1; off < 16; off <<= 1) {
      s  += __shfl_xor(s, off);
      ss += __shfl_xor(ss, off);
    }
    if (ln == 0) {
      const int row = mt * 16 + q * 4 + r;
      partials[((size_t)w * 32 + row) * 2 + 0] = s;
      partials[((size_t)w * 32 + row) * 2 + 1] = ss;
    }
  }
  // zero the 16 rows this block doesn't own (uniform partials layout)
  if (lane < 16) {
    const int row = (1 - mt) * 16 + lane;
    partials[((size_t)w * 32 + row) * 2 + 0] = 0.f;
    partials[((size_t)w * 32 + row) * 2 + 1] = 0.f;
  }
}

// ---------------- per-step GEMM fallback (fp32, small ws) ----------------

__launch_bounds__(256)
__global__ void step_gemm_f32(const float* __restrict__ x, const float* __restrict__ hf,
                              const float* __restrict__ W, const float* __restrict__ bias,
                              float* __restrict__ comb, float* __restrict__ partials,
                              int t) {
  const int blk = blockIdx.x;          // 256 blocks * 16 cols
  const int tid = threadIdx.x;
  const int n   = blk * 16 + (tid & 15);
  const int mlo = tid >> 4;            // 0..15 ; handles rows mlo and mlo+16
  float a0 = 0.f, a1 = 0.f;
  for (int k = 0; k < NI; ++k) {
    const float wv = W[(size_t)k * NC + n];
    a0 += x[((size_t)mlo * NS + t) * NI + k] * wv;
    a1 += x[((size_t)(mlo + 16) * NS + t) * NI + k] * wv;
  }
  for (int k = 0; k < NO; ++k) {
    const float wv = W[(size_t)(NI + k) * NC + n];
    a0 += hf[mlo * NO + k] * wv;
    a1 += hf[(mlo + 16) * NO + k] * wv;
  }
  a0 += bias[n];
  a1 += bias[n];
  comb[(size_t)mlo * NC + n] = a0;
  comb[(size_t)(mlo + 16) * NC + n] = a1;
  __shared__ float sred[32][16], ssred[32][16];
  sred[mlo][tid & 15] = a0;        ssred[mlo][tid & 15] = a0 * a0;
  sred[mlo + 16][tid & 15] = a1;   ssred[mlo + 16][tid & 15] = a1 * a1;
  __syncthreads();
  if (tid < 32) {
    float s = 0.f, ss = 0.f;
    for (int i = 0; i < 16; ++i) { s += sred[tid][i]; ss += ssred[tid][i]; }
    partials[((size_t)blk * 32 + tid) * 2 + 0] = s;
    partials[((size_t)blk * 32 + tid) * 2 + 1] = ss;
  }
}

// ---------------- per-step LN + gate update ----------------

// grid 32 x 256. Block bg owns h-cols [bg*32, bg*32+32), all 32 rows.
__launch_bounds__(256)
__global__ void step_update(const float* __restrict__ comb,
                            const float* __restrict__ partials,
                            const float* __restrict__ gamma,
                            const float* __restrict__ beta,
                            float* __restrict__ cst,
                            float* __restrict__ out,
                            __hip_bfloat16* __restrict__ hbf,
                            float* __restrict__ hf,
                            int t) {
  __shared__ float red[32][8][2];
  __shared__ float stat[32][2];
  const int tid = threadIdx.x;
  const int m   = tid >> 3;   // 0..31
  const int i8  = tid & 7;    // 0..7
  float s = 0.f, ss = 0.f;
  for (int i = 0; i < 32; ++i) {
    const int w = i8 * 32 + i;
    s  += partials[((size_t)w * 32 + m) * 2 + 0];
    ss += partials[((size_t)w * 32 + m) * 2 + 1];
  }
  red[m][i8][0] = s;
  red[m][i8][1] = ss;
  __syncthreads();
  if (i8 == 0) {
    for (int i = 1; i < 8; ++i) { s += red[m][i][0]; ss += red[m][i][1]; }
    const float mean = s * (1.f / NC);
    const float var  = ss * (1.f / NC) - mean * mean;
    stat[m][0] = mean;
    stat[m][1] = rsqrtf(var + LN_EPS);
  }
  __syncthreads();
  const float mean = stat[m][0];
  const float rs   = stat[m][1];
  const int jj = blockIdx.x * 32 + i8 * 4;
#pragma unroll
  for (int e = 0; e < 4; ++e) {
    const int j = jj + e;
    const float iv = (comb[(size_t)m * NC + j]          - mean) * rs * gamma[j]          + beta[j];
    const float fv = (comb[(size_t)m * NC + NO + j]     - mean) * rs * gamma[NO + j]     + beta[NO + j];
    const float gv = (comb[(size_t)m * NC + 2 * NO + j] - mean) * rs * gamma[2 * NO + j] + beta[2 * NO + j];
    const float ov = (comb[(size_t)m * NC + 3 * NO + j] - mean) * rs * gamma[3 * NO + j] + beta[3 * NO + j];
    const float cc = sigf(fv) * cst[m * NO + j] + sigf(iv) * tanhf(gv);
    const float hh = sigf(ov) * cc;
    cst[m * NO + j] = cc;
    out[((size_t)m * NS + t) * NO + j] = hh;
    hf[m * NO + j]  = hh;
    hbf[m * NO + j] = __float2bfloat16(hh);
  }
}

// ---------------- launch ----------------

extern "C" void kernel_launch(void* const* d_in, const int* in_sizes, int n_in,
                              void* d_out, int out_size, void* d_ws, size_t ws_size,
                              hipStream_t stream) {
  (void)in_sizes; (void)n_in; (void)out_size;
  const float* x     = (const float*)d_in[0];
  const float* W     = (const float*)d_in[1];
  const float* bias  = (const float*)d_in[2];
  const float* gamma = (const float*)d_in[3];
  const float* beta  = (const float*)d_in[4];
  const float* hx0   = (const float*)d_in[5];
  const float* cx0   = (const float*)d_in[6];
  float* out = (float*)d_out;

  char* ws = (char*)d_ws;
  size_t off = 0;
  auto alloc = [&](size_t bytes) -> char* {
    off = (off + 255) & ~(size_t)255;
    char* p = ws + off;
    off += bytes;
    return p;
  };
  float* comb          = (float*)alloc((size_t)NB * NC * 4);
  float* cst           = (float*)alloc((size_t)NB * NO * 4);
  float* hf            = (float*)alloc((size_t)NB * NO * 4);
  __hip_bfloat16* hbf  = (__hip_bfloat16*)alloc((size_t)NB * NO * 2);
  float* partials      = (float*)alloc((size_t)256 * 32 * 2 * 4);
  __hip_bfloat16* xbf  = (__hip_bfloat16*)alloc((size_t)NB * NS * NI * 2);
  __hip_bfloat16* WT   = (__hip_bfloat16*)alloc((size_t)NC * NK * 2);
  const bool big = (ws_size >= off);   // constant across calls -> same work every call

  hipLaunchKernelGGL(init_state, dim3((NB * NO) / 256), dim3(256), 0, stream,
                     hx0, cx0, hbf, cst, hf);
  if (big) {
    hipLaunchKernelGGL(convert_x, dim3((NB * NS * NI) / (256 * 4)), dim3(256), 0, stream,
                       x, xbf);
    hipLaunchKernelGGL(transpose_w, dim3((NK / 64) * (NC / 64)), dim3(256), 0, stream,
                       W, WT);
  }
  for (int t = 0; t < NS; ++t) {
    if (big)
      hipLaunchKernelGGL(step_gemm, dim3(256), dim3(64), 0, stream,
                         xbf, hbf, WT, bias, comb, partials, t);
    else
      hipLaunchKernelGGL(step_gemm_f32, dim3(256), dim3(256), 0, stream,
                         x, hf, W, bias, comb, partials, t);
    hipLaunchKernelGGL(step_update, dim3(32), dim3(256), 0, stream,
                       comb, partials, gamma, beta, cst, out, hbf, hf, t);
  }
}